// Round 8
// baseline (834.232 us; speedup 1.0000x reference)
//
#include <hip/hip_runtime.h>
#include <cstdint>
#include <cstddef>

typedef short bf16x8 __attribute__((ext_vector_type(8)));
typedef float f32x4 __attribute__((ext_vector_type(4)));

#define HH 48
#define WW 64
#define HWSZ 3072
#define SCALE_Q 0.08838834764831845f

__device__ __forceinline__ float b2f(unsigned short u) {
    union { unsigned int i; float f; } c; c.i = ((unsigned int)u) << 16; return c.f;
}
__device__ __forceinline__ unsigned short f2b(float f) {
    union { float f; unsigned int i; } c; c.f = f;
    unsigned int r = (c.i + 0x7fffu + ((c.i >> 16) & 1u)) >> 16;
    return (unsigned short)r;
}

// ---------------- K0a: fmap (fb, c, pos) f32 -> Xb (fb, pos, c) bf16 ----------------
__global__ __launch_bounds__(256) void k_transpose(const float* __restrict__ f0,
                                                   const float* __restrict__ f1,
                                                   unsigned short* __restrict__ Xb) {
    __shared__ float t[32][33];
    int fb = blockIdx.z; int f = fb >> 1, bb = fb & 1;
    const float* src = f ? f1 : f0;
    int pT = blockIdx.x * 32, cT = blockIdx.y * 32;
    int tx = threadIdx.x, ty = threadIdx.y;
#pragma unroll
    for (int i = 0; i < 4; ++i) {
        int c = cT + ty + i * 8, pos = pT + tx;
        t[ty + i * 8][tx] = src[(size_t)(bb * 128 + c) * HWSZ + pos];
    }
    __syncthreads();
#pragma unroll
    for (int i = 0; i < 4; ++i) {
        int pos = pT + ty + i * 8, c = cT + tx;
        Xb[(size_t)(fb * HWSZ + pos) * 128 + c] = f2b(t[tx][ty + i * 8]);
    }
}

// ---------------- K0b: weights -> bf16 ----------------
__global__ __launch_bounds__(256) void k_weights(const float* __restrict__ Wqk,
                                                 const float* __restrict__ Wv,
                                                 const float* __restrict__ Wp,
                                                 unsigned short* __restrict__ Wcat,
                                                 unsigned short* __restrict__ Wpb) {
    int idx = blockIdx.x * 256 + threadIdx.x;
    if (idx < 131072) {
        int o = idx >> 7, c = idx & 127;
        float v = (o < 512) ? Wqk[o * 128 + c] * SCALE_Q : Wv[(o - 512) * 128 + c];
        Wcat[idx] = f2b(v);
    } else {
        int j = idx - 131072;
        Wpb[j] = f2b(Wp[j]);
    }
}

// ---------------- K1: q/v projections ----------------
__global__ __launch_bounds__(256) void k_qv(const unsigned short* __restrict__ Xb,
                                            const unsigned short* __restrict__ Wcat,
                                            unsigned short* __restrict__ Qx,
                                            unsigned short* __restrict__ Vt) {
    __shared__ unsigned short Asub[64 * 136];
    __shared__ unsigned short Bsub[128 * 136];
    int mt = blockIdx.x, nt = blockIdx.y, fb = blockIdx.z;
    int tid = threadIdx.x;
    const unsigned short* asrc = Xb + (size_t)(fb * HWSZ + mt * 64) * 128;
    const unsigned short* bsrc = Wcat + (size_t)nt * 128 * 128;
    for (int ch = tid; ch < 1024; ch += 256) {
        int row = ch >> 4, seg = ch & 15;
        *(bf16x8*)&Asub[row * 136 + seg * 8] = *(const bf16x8*)(asrc + ch * 8);
    }
    for (int ch = tid; ch < 2048; ch += 256) {
        int row = ch >> 4, seg = ch & 15;
        *(bf16x8*)&Bsub[row * 136 + seg * 8] = *(const bf16x8*)(bsrc + ch * 8);
    }
    __syncthreads();
    int l = tid & 63, w = tid >> 6;
    int wm = w >> 1, wn = w & 1;
    int lr = l & 15, lk8 = (l >> 4) * 8;
    f32x4 acc[2][4] = {};
#pragma unroll
    for (int kt = 0; kt < 4; ++kt) {
        bf16x8 a[2], b[4];
#pragma unroll
        for (int m = 0; m < 2; ++m)
            a[m] = *(const bf16x8*)&Asub[(wm * 32 + m * 16 + lr) * 136 + kt * 32 + lk8];
#pragma unroll
        for (int n = 0; n < 4; ++n)
            b[n] = *(const bf16x8*)&Bsub[(wn * 64 + n * 16 + lr) * 136 + kt * 32 + lk8];
#pragma unroll
        for (int m = 0; m < 2; ++m)
#pragma unroll
            for (int n = 0; n < 4; ++n)
                acc[m][n] = __builtin_amdgcn_mfma_f32_16x16x32_bf16(a[m], b[n], acc[m][n], 0, 0, 0);
    }
    int f = fb >> 1, bb = fb & 1;
#pragma unroll
    for (int m = 0; m < 2; ++m)
#pragma unroll
        for (int n = 0; n < 4; ++n) {
            int o = nt * 128 + wn * 64 + n * 16 + lr;
            int pos0 = mt * 64 + wm * 32 + m * 16 + (l >> 4) * 4;
            if (o < 512) {
                int nh = o >> 7, d = o & 127;
#pragma unroll
                for (int r = 0; r < 4; ++r) {
                    int pos = pos0 + r, x = pos >> 6, y = pos & 63;
                    Qx[(size_t)((f * 48 + x) * 512 + (bb * 4 + nh) * 64 + y) * 128 + d] = f2b(acc[m][n][r]);
                }
            } else {
                int oo = o - 512, nh = oo >> 7, d = oo & 127;
                uint2 val;
                val.x = (unsigned int)f2b(acc[m][n][0]) | ((unsigned int)f2b(acc[m][n][1]) << 16);
                val.y = (unsigned int)f2b(acc[m][n][2]) | ((unsigned int)f2b(acc[m][n][3]) << 16);
                *(uint2*)&Vt[(size_t)((fb * 4 + nh) * 128 + d) * HWSZ + pos0] = val;
            }
        }
}

// ---------------- K2a: ph softmax over u ----------------
__global__ __launch_bounds__(256) void k_ph(const unsigned short* __restrict__ Qx,
                                            const float* __restrict__ rel_h,
                                            unsigned short* __restrict__ PH) {
    __shared__ float sm[4][16][52];
    int x = blockIdx.x, f = blockIdx.y;
    int tid = threadIdx.x, l = tid & 63, w = tid >> 6;
    int lr = l & 15, lk8 = (l >> 4) * 8;
    bf16x8 bh[3][4];
#pragma unroll
    for (int ut = 0; ut < 3; ++ut) {
        int u = ut * 16 + lr, rr = x - u + 99;
#pragma unroll
        for (int kt = 0; kt < 4; ++kt) {
            const float* s = rel_h + rr * 128 + kt * 32 + lk8;
            float4 a0 = *(const float4*)s, a1 = *(const float4*)(s + 4);
            bf16x8 pk;
            pk[0] = (short)f2b(a0.x); pk[1] = (short)f2b(a0.y); pk[2] = (short)f2b(a0.z); pk[3] = (short)f2b(a0.w);
            pk[4] = (short)f2b(a1.x); pk[5] = (short)f2b(a1.y); pk[6] = (short)f2b(a1.z); pk[7] = (short)f2b(a1.w);
            bh[ut][kt] = pk;
        }
    }
    const unsigned short* qbase = Qx + (size_t)(f * 48 + x) * 512 * 128;
    unsigned short* phbase = PH + (size_t)(f * 48 + x) * 512 * 48;
    for (int mt = 0; mt < 8; ++mt) {
        int rg = w * 128 + mt * 16 + lr;
        const unsigned short* qrow = qbase + (size_t)rg * 128;
        bf16x8 a[4];
#pragma unroll
        for (int kt = 0; kt < 4; ++kt) a[kt] = *(const bf16x8*)(qrow + kt * 32 + lk8);
        f32x4 acc[3] = {};
#pragma unroll
        for (int kt = 0; kt < 4; ++kt)
#pragma unroll
            for (int ut = 0; ut < 3; ++ut)
                acc[ut] = __builtin_amdgcn_mfma_f32_16x16x32_bf16(a[kt], bh[ut][kt], acc[ut], 0, 0, 0);
        __syncthreads();
#pragma unroll
        for (int ut = 0; ut < 3; ++ut)
#pragma unroll
            for (int r = 0; r < 4; ++r)
                sm[w][(l >> 4) * 4 + r][ut * 16 + lr] = acc[ut][r];
        __syncthreads();
        int part = l >> 4;
        float vb[12];
        float mx = -1e30f;
#pragma unroll
        for (int j = 0; j < 12; ++j) { vb[j] = sm[w][lr][part * 12 + j]; mx = fmaxf(mx, vb[j]); }
        mx = fmaxf(mx, __shfl_xor(mx, 16, 64));
        mx = fmaxf(mx, __shfl_xor(mx, 32, 64));
        float ssum = 0.f;
#pragma unroll
        for (int j = 0; j < 12; ++j) { vb[j] = __expf(vb[j] - mx); ssum += vb[j]; }
        ssum += __shfl_xor(ssum, 16, 64);
        ssum += __shfl_xor(ssum, 32, 64);
        float inv = 1.0f / ssum;
        unsigned short* dst = phbase + (size_t)(w * 128 + mt * 16 + lr) * 48 + part * 12;
#pragma unroll
        for (int j = 0; j < 12; ++j) dst[j] = f2b(vb[j] * inv);
    }
}

// ---------------- K2b: pw softmax over v ----------------
__global__ __launch_bounds__(256) void k_pw(const unsigned short* __restrict__ Qx,
                                            const float* __restrict__ rel_w,
                                            unsigned short* __restrict__ PW) {
    __shared__ float sm[4][16][68];
    int y = blockIdx.x, f = blockIdx.y;
    int tid = threadIdx.x, l = tid & 63, w = tid >> 6;
    int lr = l & 15, lk8 = (l >> 4) * 8;
    bf16x8 bw[4][4];
#pragma unroll
    for (int vt = 0; vt < 4; ++vt) {
        int v = vt * 16 + lr, rr = y - v + 99;
#pragma unroll
        for (int kt = 0; kt < 4; ++kt) {
            const float* s = rel_w + rr * 128 + kt * 32 + lk8;
            float4 a0 = *(const float4*)s, a1 = *(const float4*)(s + 4);
            bf16x8 pk;
            pk[0] = (short)f2b(a0.x); pk[1] = (short)f2b(a0.y); pk[2] = (short)f2b(a0.z); pk[3] = (short)f2b(a0.w);
            pk[4] = (short)f2b(a1.x); pk[5] = (short)f2b(a1.y); pk[6] = (short)f2b(a1.z); pk[7] = (short)f2b(a1.w);
            bw[vt][kt] = pk;
        }
    }
    for (int mt = 0; mt < 6; ++mt) {
        int rg = w * 96 + mt * 16 + lr;
        int bn = rg / 48, xx = rg - bn * 48;
        const unsigned short* qrow = Qx + (size_t)((f * 48 + xx) * 512 + bn * 64 + y) * 128;
        bf16x8 a[4];
#pragma unroll
        for (int kt = 0; kt < 4; ++kt) a[kt] = *(const bf16x8*)(qrow + kt * 32 + lk8);
        f32x4 acc[4] = {};
#pragma unroll
        for (int kt = 0; kt < 4; ++kt)
#pragma unroll
            for (int vt = 0; vt < 4; ++vt)
                acc[vt] = __builtin_amdgcn_mfma_f32_16x16x32_bf16(a[kt], bw[vt][kt], acc[vt], 0, 0, 0);
        __syncthreads();
#pragma unroll
        for (int vt = 0; vt < 4; ++vt)
#pragma unroll
            for (int r = 0; r < 4; ++r)
                sm[w][(l >> 4) * 4 + r][vt * 16 + lr] = acc[vt][r];
        __syncthreads();
        int part = l >> 4;
        float vb[16];
        float mx = -1e30f;
#pragma unroll
        for (int j = 0; j < 16; ++j) { vb[j] = sm[w][lr][part * 16 + j]; mx = fmaxf(mx, vb[j]); }
        mx = fmaxf(mx, __shfl_xor(mx, 16, 64));
        mx = fmaxf(mx, __shfl_xor(mx, 32, 64));
        float ssum = 0.f;
#pragma unroll
        for (int j = 0; j < 16; ++j) { vb[j] = __expf(vb[j] - mx); ssum += vb[j]; }
        ssum += __shfl_xor(ssum, 16, 64);
        ssum += __shfl_xor(ssum, 32, 64);
        float inv = 1.0f / ssum;
        unsigned short* dst = PW + (size_t)((f * 64 + y) * 384 + rg) * 64 + part * 16;
#pragma unroll
        for (int j = 0; j < 16; ++j) dst[j] = f2b(vb[j] * inv);
    }
}

// ---------------- K3 v4: 4-wave blocks (96q x 64d), bf16 ph, depth-2 triple-rotation prefetch ----------------
// Grid 1024 = (32 q-tiles x 2 d-halves) x 16 fbn; 256 threads (4 waves, each all 96 q x 16 d).
__global__ __launch_bounds__(256, 4) void k_attn(const unsigned short* __restrict__ PH,
                                                 const unsigned short* __restrict__ PW,
                                                 const unsigned short* __restrict__ Vt,
                                                 unsigned short* __restrict__ AO) {
    __shared__ unsigned short phl[48 * 96];        // [u][q] bf16, broadcast reads (9216 B)
    __shared__ unsigned short vbuf[2][64 * 64];    // [d][key-chunk swizzled] (2 x 8192 B)
    int bid = blockIdx.x;
    int r16 = bid & 15;
    int rest = bid >> 4;                            // 0..63
    int t = rest >> 1, dh = rest & 1;               // q-tile (96 rows), d-half
    int fbn = (r16 & 7) * 2 + (r16 >> 3);           // XCD-local V reuse
    int f = fbn >> 3, bidx = (fbn >> 2) & 1, nh = fbn & 3;
    int fb = f * 2 + bidx, bn = bidx * 4 + nh;
    int tid = threadIdx.x;
    int l = tid & 63, wn = tid >> 6;                // wave = d-slice
    int lr = l & 15, lg = l >> 4, lk8 = lg * 8;

    // V staging: thread -> (d-row sd, chunks sch and sch+4); coalesced global, swizzled LDS
    const unsigned short* vsrc = Vt + (size_t)((fb * 4 + nh) * 128 + dh * 64) * HWSZ;
    int sd = tid >> 2, sch = tid & 3;
    const unsigned short* vsrow0 = vsrc + (size_t)sd * HWSZ + sch * 8;
    const unsigned short* vsrow1 = vsrow0 + 32;
    int vdoff0 = sd * 64 + ((sch ^ (sd & 7)) * 8);
    int vdoff1 = sd * 64 + (((sch + 4) ^ (sd & 7)) * 8);

    // issue first three tiles early (latency hides under phl/A staging)
    bf16x8 r0a = *(const bf16x8*)(vsrow0);
    bf16x8 r0b = *(const bf16x8*)(vsrow1);
    bf16x8 r1a = *(const bf16x8*)(vsrow0 + 64);
    bf16x8 r1b = *(const bf16x8*)(vsrow1 + 64);
    bf16x8 r2a = *(const bf16x8*)(vsrow0 + 128);
    bf16x8 r2b = *(const bf16x8*)(vsrow1 + 128);

    // stage ph transposed [u][q] as bf16 (conflict-free: consecutive tid -> consecutive q)
    for (int i = tid; i < 2304; i += 256) {
        int up = i / 96, q = i - up * 96;
        int xy = t * 96 + q, x = xy >> 6, y = xy & 63;
        unsigned int wv = *(const unsigned int*)(PH + ((size_t)(f * 48 + x) * 512 + bn * 64 + y) * 48 + up * 2);
        phl[(up * 2) * 96 + q]     = (unsigned short)(wv & 0xffffu);
        phl[(up * 2 + 1) * 96 + q] = (unsigned short)(wv >> 16);
    }
    // pw A-fragments (6 m-frags x 2 k-halves) in registers
    bf16x8 a[6][2];
#pragma unroll
    for (int m = 0; m < 6; ++m) {
        int xy = t * 96 + m * 16 + lr;
        int x = xy >> 6, y = xy & 63;
        const unsigned short* pwr = PW + ((size_t)(f * 64 + y) * 384 + bn * 48 + x) * 64;
        a[m][0] = *(const bf16x8*)(pwr + lk8);
        a[m][1] = *(const bf16x8*)(pwr + 32 + lk8);
    }
    // stage tile 0
    *(bf16x8*)&vbuf[0][vdoff0] = r0a;
    *(bf16x8*)&vbuf[0][vdoff1] = r0b;
    __syncthreads();

    int rrow = wn * 16 + lr;
    int bo0 = rrow * 64 + ((lg ^ (rrow & 7)) * 8);
    int bo1 = rrow * 64 + (((4 + lg) ^ (rrow & 7)) * 8);
    int ph_lg = lg * 4;
    f32x4 out_acc[6] = {};
    const f32x4 zero4 = {0.f, 0.f, 0.f, 0.f};

#define KSTEP(U, CUR, LA, LB, WA, WB)                                                      \
    {                                                                                      \
        if ((U) + 3 < 48) {                                                                \
            LA = *(const bf16x8*)(vsrow0 + (size_t)((U) + 3) * 64);                        \
            LB = *(const bf16x8*)(vsrow1 + (size_t)((U) + 3) * 64);                        \
        }                                                                                  \
        bf16x8 b0_ = *(const bf16x8*)&vbuf[CUR][bo0];                                      \
        bf16x8 b1_ = *(const bf16x8*)&vbuf[CUR][bo1];                                      \
        _Pragma("unroll")                                                                  \
        for (int m_ = 0; m_ < 6; ++m_) {                                                   \
            f32x4 Y_ = __builtin_amdgcn_mfma_f32_16x16x32_bf16(a[m_][0], b0_, zero4, 0, 0, 0); \
            Y_ = __builtin_amdgcn_mfma_f32_16x16x32_bf16(a[m_][1], b1_, Y_, 0, 0, 0);      \
            ushort4 pp_ = *(const ushort4*)&phl[(U) * 96 + m_ * 16 + ph_lg];               \
            f32x4 phv_;                                                                    \
            phv_[0] = b2f(pp_.x); phv_[1] = b2f(pp_.y);                                    \
            phv_[2] = b2f(pp_.z); phv_[3] = b2f(pp_.w);                                    \
            out_acc[m_] += phv_ * Y_;                                                      \
        }                                                                                  \
        if ((U) < 47) {                                                                    \
            *(bf16x8*)&vbuf[(CUR) ^ 1][vdoff0] = WA;                                       \
            *(bf16x8*)&vbuf[(CUR) ^ 1][vdoff1] = WB;                                       \
        }                                                                                  \
        __syncthreads();                                                                   \
    }

    for (int uu = 0; uu < 48; uu += 6) {
        KSTEP(uu + 0, 0, r0a, r0b, r1a, r1b);
        KSTEP(uu + 1, 1, r1a, r1b, r2a, r2b);
        KSTEP(uu + 2, 0, r2a, r2b, r0a, r0b);
        KSTEP(uu + 3, 1, r0a, r0b, r1a, r1b);
        KSTEP(uu + 4, 0, r1a, r1b, r2a, r2b);
        KSTEP(uu + 5, 1, r2a, r2b, r0a, r0b);
    }
#undef KSTEP

    unsigned short* aobase = AO + (size_t)fb * HWSZ * 512 + nh * 128;
    int dcol = dh * 64 + rrow;
#pragma unroll
    for (int m = 0; m < 6; ++m) {
        int q0 = t * 96 + m * 16 + lg * 4;
#pragma unroll
        for (int r = 0; r < 4; ++r)
            aobase[(size_t)(q0 + r) * 512 + dcol] = f2b(out_acc[m][r]);
    }
}

// ---------------- K4: out = fmap + gamma * (AO @ Wp^T) ----------------
__global__ __launch_bounds__(256) void k_proj(const unsigned short* __restrict__ AO,
                                              const unsigned short* __restrict__ Wpb,
                                              const float* __restrict__ f0,
                                              const float* __restrict__ f1,
                                              const float* __restrict__ gamma,
                                              float* __restrict__ out) {
    __shared__ unsigned short Asub[64 * 136];
    __shared__ unsigned short Bsub[128 * 136];
    int t = blockIdx.x, fb = blockIdx.y;
    int f = fb >> 1, bb = fb & 1;
    int tid = threadIdx.x;
    int l = tid & 63, w = tid >> 6;
    int wm = w >> 1, wn = w & 1;
    int lr = l & 15, lk8 = (l >> 4) * 8;
    f32x4 acc[2][4] = {};
    for (int ks = 0; ks < 4; ++ks) {
        if (ks) __syncthreads();
        for (int ch = tid; ch < 1024; ch += 256) {
            int row = ch >> 4, seg = ch & 15;
            *(bf16x8*)&Asub[row * 136 + seg * 8] =
                *(const bf16x8*)(AO + (size_t)(fb * HWSZ + t * 64 + row) * 512 + ks * 128 + seg * 8);
        }
        for (int ch = tid; ch < 2048; ch += 256) {
            int row = ch >> 4, seg = ch & 15;
            *(bf16x8*)&Bsub[row * 136 + seg * 8] =
                *(const bf16x8*)(Wpb + (size_t)row * 512 + ks * 128 + seg * 8);
        }
        __syncthreads();
#pragma unroll
        for (int kt = 0; kt < 4; ++kt) {
            bf16x8 a[2], b[4];
#pragma unroll
            for (int m = 0; m < 2; ++m)
                a[m] = *(const bf16x8*)&Asub[(wm * 32 + m * 16 + lr) * 136 + kt * 32 + lk8];
#pragma unroll
            for (int n = 0; n < 4; ++n)
                b[n] = *(const bf16x8*)&Bsub[(wn * 64 + n * 16 + lr) * 136 + kt * 32 + lk8];
#pragma unroll
            for (int m = 0; m < 2; ++m)
#pragma unroll
                for (int n = 0; n < 4; ++n)
                    acc[m][n] = __builtin_amdgcn_mfma_f32_16x16x32_bf16(a[m], b[n], acc[m][n], 0, 0, 0);
        }
    }
    const float* fmapf = f ? f1 : f0;
    float g = gamma[0];
#pragma unroll
    for (int m = 0; m < 2; ++m)
#pragma unroll
        for (int n = 0; n < 4; ++n) {
            int c = wn * 64 + n * 16 + lr;
            int pos0 = t * 64 + wm * 32 + m * 16 + (l >> 4) * 4;
            size_t addr = (size_t)(bb * 128 + c) * HWSZ + pos0;
            float4 fv = *(const float4*)(fmapf + addr);
            float4 ov;
            ov.x = fv.x + g * acc[m][n][0];
            ov.y = fv.y + g * acc[m][n][1];
            ov.z = fv.z + g * acc[m][n][2];
            ov.w = fv.w + g * acc[m][n][3];
            *(float4*)(out + (size_t)f * 786432 + addr) = ov;
        }
}

extern "C" void kernel_launch(void* const* d_in, const int* in_sizes, int n_in,
                              void* d_out, int out_size, void* d_ws, size_t ws_size,
                              hipStream_t stream) {
    (void)in_sizes; (void)n_in; (void)out_size; (void)ws_size;
    const float* fmap1 = (const float*)d_in[0];
    const float* fmap2 = (const float*)d_in[1];
    const float* Wqk   = (const float*)d_in[2];
    const float* Wv    = (const float*)d_in[3];
    const float* rel_h = (const float*)d_in[4];
    const float* rel_w = (const float*)d_in[5];
    const float* Wp    = (const float*)d_in[6];
    const float* gamma = (const float*)d_in[7];
    float* out = (float*)d_out;
    char* ws = (char*)d_ws;

    unsigned short* Xb   = (unsigned short*)(ws + 0);
    unsigned short* Wcat = (unsigned short*)(ws + 3145728);
    unsigned short* Wpb  = (unsigned short*)(ws + 3407872);
    unsigned short* Qx   = (unsigned short*)(ws + 3538944);
    unsigned short* AO   = Qx;                               // alias: Qx dead after K2
    unsigned short* Vt   = (unsigned short*)(ws + 16121856);
    unsigned short* PH   = (unsigned short*)(ws + 28704768);
    unsigned short* PW   = (unsigned short*)(ws + 33423360);

    k_transpose<<<dim3(96, 4, 4), dim3(32, 8), 0, stream>>>(fmap1, fmap2, Xb);
    k_weights<<<dim3(768), dim3(256), 0, stream>>>(Wqk, Wv, Wp, Wcat, Wpb);
    k_qv<<<dim3(48, 8, 4), dim3(256), 0, stream>>>(Xb, Wcat, Qx, Vt);
    k_ph<<<dim3(48, 2), dim3(256), 0, stream>>>(Qx, rel_h, PH);
    k_pw<<<dim3(64, 2), dim3(256), 0, stream>>>(Qx, rel_w, PW);
    k_attn<<<dim3(1024), dim3(256), 0, stream>>>(PH, PW, Vt, AO);
    k_proj<<<dim3(48, 4), dim3(256), 0, stream>>>(AO, Wpb, fmap1, fmap2, gamma, out);
}

// Round 9
// 118.250 us; speedup vs baseline: 7.0548x; 7.0548x over previous
//
#include <hip/hip_runtime.h>
#include <cstdint>
#include <cstddef>

typedef short bf16x8 __attribute__((ext_vector_type(8)));
typedef float f32x4 __attribute__((ext_vector_type(4)));

#define HH 48
#define WW 64
#define HWSZ 3072
#define SCALE_Q 0.08838834764831845f

__device__ __forceinline__ float b2f(unsigned short u) {
    union { unsigned int i; float f; } c; c.i = ((unsigned int)u) << 16; return c.f;
}
__device__ __forceinline__ unsigned short f2b(float f) {
    union { float f; unsigned int i; } c; c.f = f;
    unsigned int r = (c.i + 0x7fffu + ((c.i >> 16) & 1u)) >> 16;
    return (unsigned short)r;
}

// ---------------- K0a: fmap (fb, c, pos) f32 -> Xb (fb, pos, c) bf16 ----------------
__global__ __launch_bounds__(256) void k_transpose(const float* __restrict__ f0,
                                                   const float* __restrict__ f1,
                                                   unsigned short* __restrict__ Xb) {
    __shared__ float t[32][33];
    int fb = blockIdx.z; int f = fb >> 1, bb = fb & 1;
    const float* src = f ? f1 : f0;
    int pT = blockIdx.x * 32, cT = blockIdx.y * 32;
    int tx = threadIdx.x, ty = threadIdx.y;
#pragma unroll
    for (int i = 0; i < 4; ++i) {
        int c = cT + ty + i * 8, pos = pT + tx;
        t[ty + i * 8][tx] = src[(size_t)(bb * 128 + c) * HWSZ + pos];
    }
    __syncthreads();
#pragma unroll
    for (int i = 0; i < 4; ++i) {
        int pos = pT + ty + i * 8, c = cT + tx;
        Xb[(size_t)(fb * HWSZ + pos) * 128 + c] = f2b(t[tx][ty + i * 8]);
    }
}

// ---------------- K0b: weights -> bf16 ----------------
__global__ __launch_bounds__(256) void k_weights(const float* __restrict__ Wqk,
                                                 const float* __restrict__ Wv,
                                                 const float* __restrict__ Wp,
                                                 unsigned short* __restrict__ Wcat,
                                                 unsigned short* __restrict__ Wpb) {
    int idx = blockIdx.x * 256 + threadIdx.x;
    if (idx < 131072) {
        int o = idx >> 7, c = idx & 127;
        float v = (o < 512) ? Wqk[o * 128 + c] * SCALE_Q : Wv[(o - 512) * 128 + c];
        Wcat[idx] = f2b(v);
    } else {
        int j = idx - 131072;
        Wpb[j] = f2b(Wp[j]);
    }
}

// ---------------- K1: q/v projections ----------------
__global__ __launch_bounds__(256) void k_qv(const unsigned short* __restrict__ Xb,
                                            const unsigned short* __restrict__ Wcat,
                                            unsigned short* __restrict__ Qx,
                                            unsigned short* __restrict__ Vt) {
    __shared__ unsigned short Asub[64 * 136];
    __shared__ unsigned short Bsub[128 * 136];
    int mt = blockIdx.x, nt = blockIdx.y, fb = blockIdx.z;
    int tid = threadIdx.x;
    const unsigned short* asrc = Xb + (size_t)(fb * HWSZ + mt * 64) * 128;
    const unsigned short* bsrc = Wcat + (size_t)nt * 128 * 128;
    for (int ch = tid; ch < 1024; ch += 256) {
        int row = ch >> 4, seg = ch & 15;
        *(bf16x8*)&Asub[row * 136 + seg * 8] = *(const bf16x8*)(asrc + ch * 8);
    }
    for (int ch = tid; ch < 2048; ch += 256) {
        int row = ch >> 4, seg = ch & 15;
        *(bf16x8*)&Bsub[row * 136 + seg * 8] = *(const bf16x8*)(bsrc + ch * 8);
    }
    __syncthreads();
    int l = tid & 63, w = tid >> 6;
    int wm = w >> 1, wn = w & 1;
    int lr = l & 15, lk8 = (l >> 4) * 8;
    f32x4 acc[2][4] = {};
#pragma unroll
    for (int kt = 0; kt < 4; ++kt) {
        bf16x8 a[2], b[4];
#pragma unroll
        for (int m = 0; m < 2; ++m)
            a[m] = *(const bf16x8*)&Asub[(wm * 32 + m * 16 + lr) * 136 + kt * 32 + lk8];
#pragma unroll
        for (int n = 0; n < 4; ++n)
            b[n] = *(const bf16x8*)&Bsub[(wn * 64 + n * 16 + lr) * 136 + kt * 32 + lk8];
#pragma unroll
        for (int m = 0; m < 2; ++m)
#pragma unroll
            for (int n = 0; n < 4; ++n)
                acc[m][n] = __builtin_amdgcn_mfma_f32_16x16x32_bf16(a[m], b[n], acc[m][n], 0, 0, 0);
    }
    int f = fb >> 1, bb = fb & 1;
#pragma unroll
    for (int m = 0; m < 2; ++m)
#pragma unroll
        for (int n = 0; n < 4; ++n) {
            int o = nt * 128 + wn * 64 + n * 16 + lr;
            int pos0 = mt * 64 + wm * 32 + m * 16 + (l >> 4) * 4;
            if (o < 512) {
                int nh = o >> 7, d = o & 127;
#pragma unroll
                for (int r = 0; r < 4; ++r) {
                    int pos = pos0 + r, x = pos >> 6, y = pos & 63;
                    Qx[(size_t)((f * 48 + x) * 512 + (bb * 4 + nh) * 64 + y) * 128 + d] = f2b(acc[m][n][r]);
                }
            } else {
                int oo = o - 512, nh = oo >> 7, d = oo & 127;
                uint2 val;
                val.x = (unsigned int)f2b(acc[m][n][0]) | ((unsigned int)f2b(acc[m][n][1]) << 16);
                val.y = (unsigned int)f2b(acc[m][n][2]) | ((unsigned int)f2b(acc[m][n][3]) << 16);
                *(uint2*)&Vt[(size_t)((fb * 4 + nh) * 128 + d) * HWSZ + pos0] = val;
            }
        }
}

// ---------------- K2a: ph softmax over u ----------------
__global__ __launch_bounds__(256) void k_ph(const unsigned short* __restrict__ Qx,
                                            const float* __restrict__ rel_h,
                                            unsigned short* __restrict__ PH) {
    __shared__ float sm[4][16][52];
    int x = blockIdx.x, f = blockIdx.y;
    int tid = threadIdx.x, l = tid & 63, w = tid >> 6;
    int lr = l & 15, lk8 = (l >> 4) * 8;
    bf16x8 bh[3][4];
#pragma unroll
    for (int ut = 0; ut < 3; ++ut) {
        int u = ut * 16 + lr, rr = x - u + 99;
#pragma unroll
        for (int kt = 0; kt < 4; ++kt) {
            const float* s = rel_h + rr * 128 + kt * 32 + lk8;
            float4 a0 = *(const float4*)s, a1 = *(const float4*)(s + 4);
            bf16x8 pk;
            pk[0] = (short)f2b(a0.x); pk[1] = (short)f2b(a0.y); pk[2] = (short)f2b(a0.z); pk[3] = (short)f2b(a0.w);
            pk[4] = (short)f2b(a1.x); pk[5] = (short)f2b(a1.y); pk[6] = (short)f2b(a1.z); pk[7] = (short)f2b(a1.w);
            bh[ut][kt] = pk;
        }
    }
    const unsigned short* qbase = Qx + (size_t)(f * 48 + x) * 512 * 128;
    unsigned short* phbase = PH + (size_t)(f * 48 + x) * 512 * 48;
    for (int mt = 0; mt < 8; ++mt) {
        int rg = w * 128 + mt * 16 + lr;
        const unsigned short* qrow = qbase + (size_t)rg * 128;
        bf16x8 a[4];
#pragma unroll
        for (int kt = 0; kt < 4; ++kt) a[kt] = *(const bf16x8*)(qrow + kt * 32 + lk8);
        f32x4 acc[3] = {};
#pragma unroll
        for (int kt = 0; kt < 4; ++kt)
#pragma unroll
            for (int ut = 0; ut < 3; ++ut)
                acc[ut] = __builtin_amdgcn_mfma_f32_16x16x32_bf16(a[kt], bh[ut][kt], acc[ut], 0, 0, 0);
        __syncthreads();
#pragma unroll
        for (int ut = 0; ut < 3; ++ut)
#pragma unroll
            for (int r = 0; r < 4; ++r)
                sm[w][(l >> 4) * 4 + r][ut * 16 + lr] = acc[ut][r];
        __syncthreads();
        int part = l >> 4;
        float vb[12];
        float mx = -1e30f;
#pragma unroll
        for (int j = 0; j < 12; ++j) { vb[j] = sm[w][lr][part * 12 + j]; mx = fmaxf(mx, vb[j]); }
        mx = fmaxf(mx, __shfl_xor(mx, 16, 64));
        mx = fmaxf(mx, __shfl_xor(mx, 32, 64));
        float ssum = 0.f;
#pragma unroll
        for (int j = 0; j < 12; ++j) { vb[j] = __expf(vb[j] - mx); ssum += vb[j]; }
        ssum += __shfl_xor(ssum, 16, 64);
        ssum += __shfl_xor(ssum, 32, 64);
        float inv = 1.0f / ssum;
        unsigned short* dst = phbase + (size_t)(w * 128 + mt * 16 + lr) * 48 + part * 12;
#pragma unroll
        for (int j = 0; j < 12; ++j) dst[j] = f2b(vb[j] * inv);
    }
}

// ---------------- K2b: pw softmax over v ----------------
__global__ __launch_bounds__(256) void k_pw(const unsigned short* __restrict__ Qx,
                                            const float* __restrict__ rel_w,
                                            unsigned short* __restrict__ PW) {
    __shared__ float sm[4][16][68];
    int y = blockIdx.x, f = blockIdx.y;
    int tid = threadIdx.x, l = tid & 63, w = tid >> 6;
    int lr = l & 15, lk8 = (l >> 4) * 8;
    bf16x8 bw[4][4];
#pragma unroll
    for (int vt = 0; vt < 4; ++vt) {
        int v = vt * 16 + lr, rr = y - v + 99;
#pragma unroll
        for (int kt = 0; kt < 4; ++kt) {
            const float* s = rel_w + rr * 128 + kt * 32 + lk8;
            float4 a0 = *(const float4*)s, a1 = *(const float4*)(s + 4);
            bf16x8 pk;
            pk[0] = (short)f2b(a0.x); pk[1] = (short)f2b(a0.y); pk[2] = (short)f2b(a0.z); pk[3] = (short)f2b(a0.w);
            pk[4] = (short)f2b(a1.x); pk[5] = (short)f2b(a1.y); pk[6] = (short)f2b(a1.z); pk[7] = (short)f2b(a1.w);
            bw[vt][kt] = pk;
        }
    }
    for (int mt = 0; mt < 6; ++mt) {
        int rg = w * 96 + mt * 16 + lr;
        int bn = rg / 48, xx = rg - bn * 48;
        const unsigned short* qrow = Qx + (size_t)((f * 48 + xx) * 512 + bn * 64 + y) * 128;
        bf16x8 a[4];
#pragma unroll
        for (int kt = 0; kt < 4; ++kt) a[kt] = *(const bf16x8*)(qrow + kt * 32 + lk8);
        f32x4 acc[4] = {};
#pragma unroll
        for (int kt = 0; kt < 4; ++kt)
#pragma unroll
            for (int vt = 0; vt < 4; ++vt)
                acc[vt] = __builtin_amdgcn_mfma_f32_16x16x32_bf16(a[kt], bw[vt][kt], acc[vt], 0, 0, 0);
        __syncthreads();
#pragma unroll
        for (int vt = 0; vt < 4; ++vt)
#pragma unroll
            for (int r = 0; r < 4; ++r)
                sm[w][(l >> 4) * 4 + r][vt * 16 + lr] = acc[vt][r];
        __syncthreads();
        int part = l >> 4;
        float vb[16];
        float mx = -1e30f;
#pragma unroll
        for (int j = 0; j < 16; ++j) { vb[j] = sm[w][lr][part * 16 + j]; mx = fmaxf(mx, vb[j]); }
        mx = fmaxf(mx, __shfl_xor(mx, 16, 64));
        mx = fmaxf(mx, __shfl_xor(mx, 32, 64));
        float ssum = 0.f;
#pragma unroll
        for (int j = 0; j < 16; ++j) { vb[j] = __expf(vb[j] - mx); ssum += vb[j]; }
        ssum += __shfl_xor(ssum, 16, 64);
        ssum += __shfl_xor(ssum, 32, 64);
        float inv = 1.0f / ssum;
        unsigned short* dst = PW + (size_t)((f * 64 + y) * 384 + rg) * 64 + part * 16;
#pragma unroll
        for (int j = 0; j < 16; ++j) dst[j] = f2b(vb[j] * inv);
    }
}

// ---------------- K3 v5: transposed MFMA (A=V, B=pw). C cols = q, rows = d. ----------------
// Grid 768 = (24 q-tiles x 2 d-halves) x 16 fbn; 256 threads = 4 waves, each 16d x 128q.
// Per step per wave: 2 V b128 + 1 ph b128 LDS reads feed 16 MFMA. pw B-frags in regs.
__global__ __launch_bounds__(256, 3) void k_attn(const unsigned short* __restrict__ PH,
                                                 const unsigned short* __restrict__ PW,
                                                 const unsigned short* __restrict__ Vt,
                                                 unsigned short* __restrict__ AO) {
    __shared__ unsigned short phl[48 * 128];       // [u][(q&15)*8 + (q>>4)] bf16 (12288 B)
    __shared__ unsigned short vbuf[2][64 * 64];    // [d][key-chunk swizzled] (2 x 8192 B)
    int bid = blockIdx.x;
    int r16 = bid & 15;
    int rest = bid >> 4;                            // 0..47
    int t = rest >> 1, dh = rest & 1;               // q-tile (128 rows), d-half
    int fbn = (r16 & 7) * 2 + (r16 >> 3);           // XCD-local V reuse
    int f = fbn >> 3, bidx = (fbn >> 2) & 1, nh = fbn & 3;
    int fb = f * 2 + bidx, bn = bidx * 4 + nh;
    int tid = threadIdx.x;
    int l = tid & 63, wd = tid >> 6;                // wave = 16-d slice
    int lr = l & 15, lg = l >> 4, lk8 = lg * 8;

    // V staging: thread -> (d-row sd, chunks sch, sch+4); coalesced global, swizzled LDS
    const unsigned short* vsrc = Vt + (size_t)((fb * 4 + nh) * 128 + dh * 64) * HWSZ;
    int sd = tid >> 2, sch = tid & 3;
    const unsigned short* vsrow0 = vsrc + (size_t)sd * HWSZ + sch * 8;
    const unsigned short* vsrow1 = vsrow0 + 32;
    int vdoff0 = sd * 64 + ((sch ^ (sd & 7)) * 8);
    int vdoff1 = sd * 64 + (((sch + 4) ^ (sd & 7)) * 8);

    bf16x8 r0a = *(const bf16x8*)(vsrow0);
    bf16x8 r0b = *(const bf16x8*)(vsrow1);

    // stage ph: packed layout [u][(q&15)*8 + (q>>4)]
    for (int i = tid; i < 3072; i += 256) {
        int up2 = i >> 7, q = i & 127;
        int xy = t * 128 + q, x = xy >> 6, y = xy & 63;
        unsigned int wv = *(const unsigned int*)(PH + ((size_t)(f * 48 + x) * 512 + bn * 64 + y) * 48 + up2 * 2);
        int qoff = (q & 15) * 8 + (q >> 4);
        phl[(up2 * 2) * 128 + qoff]     = (unsigned short)(wv & 0xffffu);
        phl[(up2 * 2 + 1) * 128 + qoff] = (unsigned short)(wv >> 16);
    }
    // pw B-fragments: 8 n-frags x 2 k-halves in registers (loaded once)
    bf16x8 b[8][2];
#pragma unroll
    for (int n = 0; n < 8; ++n) {
        int xy = t * 128 + n * 16 + lr;
        int x = xy >> 6, y = xy & 63;
        const unsigned short* pwr = PW + ((size_t)(f * 64 + y) * 384 + bn * 48 + x) * 64;
        b[n][0] = *(const bf16x8*)(pwr + lk8);
        b[n][1] = *(const bf16x8*)(pwr + 32 + lk8);
    }
    *(bf16x8*)&vbuf[0][vdoff0] = r0a;
    *(bf16x8*)&vbuf[0][vdoff1] = r0b;
    __syncthreads();

    int arow = wd * 16 + lr;
    int ao0 = arow * 64 + ((lg ^ (arow & 7)) * 8);
    int ao1 = arow * 64 + (((4 + lg) ^ (arow & 7)) * 8);
    const unsigned short* phrow = &phl[lr * 8];
    f32x4 acc[8] = {};
    const f32x4 zero4 = {0.f, 0.f, 0.f, 0.f};
    int cur = 0;
    for (int u = 0; u < 48; ++u) {
        bf16x8 ra, rb;
        if (u < 47) {
            ra = *(const bf16x8*)(vsrow0 + (size_t)(u + 1) * 64);   // issue early
            rb = *(const bf16x8*)(vsrow1 + (size_t)(u + 1) * 64);
        }
        bf16x8 av0 = *(const bf16x8*)&vbuf[cur][ao0];
        bf16x8 av1 = *(const bf16x8*)&vbuf[cur][ao1];
        bf16x8 phv = *(const bf16x8*)(phrow + u * 128);             // 8 ph scalars for this lane's q
#pragma unroll
        for (int n = 0; n < 8; ++n) {
            f32x4 Y = __builtin_amdgcn_mfma_f32_16x16x32_bf16(av0, b[n][0], zero4, 0, 0, 0);
            Y = __builtin_amdgcn_mfma_f32_16x16x32_bf16(av1, b[n][1], Y, 0, 0, 0);
            float p = b2f((unsigned short)phv[n]);
            acc[n] += p * Y;
        }
        if (u < 47) {
            *(bf16x8*)&vbuf[cur ^ 1][vdoff0] = ra;                   // write late
            *(bf16x8*)&vbuf[cur ^ 1][vdoff1] = rb;
        }
        __syncthreads();
        cur ^= 1;
    }
    // store: lane col q = t*128 + n*16 + lr; rows d = dh*64 + wd*16 + lg*4 + r (4 consecutive)
    unsigned short* aobase = AO + (size_t)fb * HWSZ * 512 + nh * 128 + dh * 64 + wd * 16 + lg * 4;
#pragma unroll
    for (int n = 0; n < 8; ++n) {
        int q = t * 128 + n * 16 + lr;
        uint2 val;
        val.x = (unsigned int)f2b(acc[n][0]) | ((unsigned int)f2b(acc[n][1]) << 16);
        val.y = (unsigned int)f2b(acc[n][2]) | ((unsigned int)f2b(acc[n][3]) << 16);
        *(uint2*)(aobase + (size_t)q * 512) = val;
    }
}

// ---------------- K4: out = fmap + gamma * (AO @ Wp^T) ----------------
__global__ __launch_bounds__(256) void k_proj(const unsigned short* __restrict__ AO,
                                              const unsigned short* __restrict__ Wpb,
                                              const float* __restrict__ f0,
                                              const float* __restrict__ f1,
                                              const float* __restrict__ gamma,
                                              float* __restrict__ out) {
    __shared__ unsigned short Asub[64 * 136];
    __shared__ unsigned short Bsub[128 * 136];
    int t = blockIdx.x, fb = blockIdx.y;
    int f = fb >> 1, bb = fb & 1;
    int tid = threadIdx.x;
    int l = tid & 63, w = tid >> 6;
    int wm = w >> 1, wn = w & 1;
    int lr = l & 15, lk8 = (l >> 4) * 8;
    f32x4 acc[2][4] = {};
    for (int ks = 0; ks < 4; ++ks) {
        if (ks) __syncthreads();
        for (int ch = tid; ch < 1024; ch += 256) {
            int row = ch >> 4, seg = ch & 15;
            *(bf16x8*)&Asub[row * 136 + seg * 8] =
                *(const bf16x8*)(AO + (size_t)(fb * HWSZ + t * 64 + row) * 512 + ks * 128 + seg * 8);
        }
        for (int ch = tid; ch < 2048; ch += 256) {
            int row = ch >> 4, seg = ch & 15;
            *(bf16x8*)&Bsub[row * 136 + seg * 8] =
                *(const bf16x8*)(Wpb + (size_t)row * 512 + ks * 128 + seg * 8);
        }
        __syncthreads();
#pragma unroll
        for (int kt = 0; kt < 4; ++kt) {
            bf16x8 a[2], b[4];
#pragma unroll
            for (int m = 0; m < 2; ++m)
                a[m] = *(const bf16x8*)&Asub[(wm * 32 + m * 16 + lr) * 136 + kt * 32 + lk8];
#pragma unroll
            for (int n = 0; n < 4; ++n)
                b[n] = *(const bf16x8*)&Bsub[(wn * 64 + n * 16 + lr) * 136 + kt * 32 + lk8];
#pragma unroll
            for (int m = 0; m < 2; ++m)
#pragma unroll
                for (int n = 0; n < 4; ++n)
                    acc[m][n] = __builtin_amdgcn_mfma_f32_16x16x32_bf16(a[m], b[n], acc[m][n], 0, 0, 0);
        }
    }
    const float* fmapf = f ? f1 : f0;
    float g = gamma[0];
#pragma unroll
    for (int m = 0; m < 2; ++m)
#pragma unroll
        for (int n = 0; n < 4; ++n) {
            int c = wn * 64 + n * 16 + lr;
            int pos0 = t * 64 + wm * 32 + m * 16 + (l >> 4) * 4;
            size_t addr = (size_t)(bb * 128 + c) * HWSZ + pos0;
            float4 fv = *(const float4*)(fmapf + addr);
            float4 ov;
            ov.x = fv.x + g * acc[m][n][0];
            ov.y = fv.y + g * acc[m][n][1];
            ov.z = fv.z + g * acc[m][n][2];
            ov.w = fv.w + g * acc[m][n][3];
            *(float4*)(out + (size_t)f * 786432 + addr) = ov;
        }
}

extern "C" void kernel_launch(void* const* d_in, const int* in_sizes, int n_in,
                              void* d_out, int out_size, void* d_ws, size_t ws_size,
                              hipStream_t stream) {
    (void)in_sizes; (void)n_in; (void)out_size; (void)ws_size;
    const float* fmap1 = (const float*)d_in[0];
    const float* fmap2 = (const float*)d_in[1];
    const float* Wqk   = (const float*)d_in[2];
    const float* Wv    = (const float*)d_in[3];
    const float* rel_h = (const float*)d_in[4];
    const float* rel_w = (const float*)d_in[5];
    const float* Wp    = (const float*)d_in[6];
    const float* gamma = (const float*)d_in[7];
    float* out = (float*)d_out;
    char* ws = (char*)d_ws;

    unsigned short* Xb   = (unsigned short*)(ws + 0);
    unsigned short* Wcat = (unsigned short*)(ws + 3145728);
    unsigned short* Wpb  = (unsigned short*)(ws + 3407872);
    unsigned short* Qx   = (unsigned short*)(ws + 3538944);
    unsigned short* AO   = Qx;                               // alias: Qx dead after K2
    unsigned short* Vt   = (unsigned short*)(ws + 16121856);
    unsigned short* PH   = (unsigned short*)(ws + 28704768);
    unsigned short* PW   = (unsigned short*)(ws + 33423360);

    k_transpose<<<dim3(96, 4, 4), dim3(32, 8), 0, stream>>>(fmap1, fmap2, Xb);
    k_weights<<<dim3(768), dim3(256), 0, stream>>>(Wqk, Wv, Wp, Wcat, Wpb);
    k_qv<<<dim3(48, 8, 4), dim3(256), 0, stream>>>(Xb, Wcat, Qx, Vt);
    k_ph<<<dim3(48, 2), dim3(256), 0, stream>>>(Qx, rel_h, PH);
    k_pw<<<dim3(64, 2), dim3(256), 0, stream>>>(Qx, rel_w, PW);
    k_attn<<<dim3(768), dim3(256), 0, stream>>>(PH, PW, Vt, AO);
    k_proj<<<dim3(48, 4), dim3(256), 0, stream>>>(AO, Wpb, fmap1, fmap2, gamma, out);
}

// Round 10
// 116.577 us; speedup vs baseline: 7.1561x; 1.0144x over previous
//
#include <hip/hip_runtime.h>
#include <cstdint>
#include <cstddef>

typedef short bf16x8 __attribute__((ext_vector_type(8)));
typedef float f32x4 __attribute__((ext_vector_type(4)));

#define HH 48
#define WW 64
#define HWSZ 3072
#define SCALE_Q 0.08838834764831845f

__device__ __forceinline__ float b2f(unsigned short u) {
    union { unsigned int i; float f; } c; c.i = ((unsigned int)u) << 16; return c.f;
}
__device__ __forceinline__ unsigned short f2b(float f) {
    union { float f; unsigned int i; } c; c.f = f;
    unsigned int r = (c.i + 0x7fffu + ((c.i >> 16) & 1u)) >> 16;
    return (unsigned short)r;
}

// ---------------- K0a: fmap (fb, c, pos) f32 -> Xb (fb, pos, c) bf16 ----------------
__global__ __launch_bounds__(256) void k_transpose(const float* __restrict__ f0,
                                                   const float* __restrict__ f1,
                                                   unsigned short* __restrict__ Xb) {
    __shared__ float t[32][33];
    int fb = blockIdx.z; int f = fb >> 1, bb = fb & 1;
    const float* src = f ? f1 : f0;
    int pT = blockIdx.x * 32, cT = blockIdx.y * 32;
    int tx = threadIdx.x, ty = threadIdx.y;
#pragma unroll
    for (int i = 0; i < 4; ++i) {
        int c = cT + ty + i * 8, pos = pT + tx;
        t[ty + i * 8][tx] = src[(size_t)(bb * 128 + c) * HWSZ + pos];
    }
    __syncthreads();
#pragma unroll
    for (int i = 0; i < 4; ++i) {
        int pos = pT + ty + i * 8, c = cT + tx;
        Xb[(size_t)(fb * HWSZ + pos) * 128 + c] = f2b(t[tx][ty + i * 8]);
    }
}

// ---------------- K0b: weights -> bf16 ----------------
__global__ __launch_bounds__(256) void k_weights(const float* __restrict__ Wqk,
                                                 const float* __restrict__ Wv,
                                                 const float* __restrict__ Wp,
                                                 unsigned short* __restrict__ Wcat,
                                                 unsigned short* __restrict__ Wpb) {
    int idx = blockIdx.x * 256 + threadIdx.x;
    if (idx < 131072) {
        int o = idx >> 7, c = idx & 127;
        float v = (o < 512) ? Wqk[o * 128 + c] * SCALE_Q : Wv[(o - 512) * 128 + c];
        Wcat[idx] = f2b(v);
    } else {
        int j = idx - 131072;
        Wpb[j] = f2b(Wp[j]);
    }
}

// ---------------- K1: q/v projections ----------------
__global__ __launch_bounds__(256) void k_qv(const unsigned short* __restrict__ Xb,
                                            const unsigned short* __restrict__ Wcat,
                                            unsigned short* __restrict__ Qx,
                                            unsigned short* __restrict__ Vt) {
    __shared__ unsigned short Asub[64 * 136];
    __shared__ unsigned short Bsub[128 * 136];
    int mt = blockIdx.x, nt = blockIdx.y, fb = blockIdx.z;
    int tid = threadIdx.x;
    const unsigned short* asrc = Xb + (size_t)(fb * HWSZ + mt * 64) * 128;
    const unsigned short* bsrc = Wcat + (size_t)nt * 128 * 128;
    for (int ch = tid; ch < 1024; ch += 256) {
        int row = ch >> 4, seg = ch & 15;
        *(bf16x8*)&Asub[row * 136 + seg * 8] = *(const bf16x8*)(asrc + ch * 8);
    }
    for (int ch = tid; ch < 2048; ch += 256) {
        int row = ch >> 4, seg = ch & 15;
        *(bf16x8*)&Bsub[row * 136 + seg * 8] = *(const bf16x8*)(bsrc + ch * 8);
    }
    __syncthreads();
    int l = tid & 63, w = tid >> 6;
    int wm = w >> 1, wn = w & 1;
    int lr = l & 15, lk8 = (l >> 4) * 8;
    f32x4 acc[2][4] = {};
#pragma unroll
    for (int kt = 0; kt < 4; ++kt) {
        bf16x8 a[2], b[4];
#pragma unroll
        for (int m = 0; m < 2; ++m)
            a[m] = *(const bf16x8*)&Asub[(wm * 32 + m * 16 + lr) * 136 + kt * 32 + lk8];
#pragma unroll
        for (int n = 0; n < 4; ++n)
            b[n] = *(const bf16x8*)&Bsub[(wn * 64 + n * 16 + lr) * 136 + kt * 32 + lk8];
#pragma unroll
        for (int m = 0; m < 2; ++m)
#pragma unroll
            for (int n = 0; n < 4; ++n)
                acc[m][n] = __builtin_amdgcn_mfma_f32_16x16x32_bf16(a[m], b[n], acc[m][n], 0, 0, 0);
    }
    int f = fb >> 1, bb = fb & 1;
#pragma unroll
    for (int m = 0; m < 2; ++m)
#pragma unroll
        for (int n = 0; n < 4; ++n) {
            int o = nt * 128 + wn * 64 + n * 16 + lr;
            int pos0 = mt * 64 + wm * 32 + m * 16 + (l >> 4) * 4;
            if (o < 512) {
                int nh = o >> 7, d = o & 127;
#pragma unroll
                for (int r = 0; r < 4; ++r) {
                    int pos = pos0 + r, x = pos >> 6, y = pos & 63;
                    Qx[(size_t)((f * 48 + x) * 512 + (bb * 4 + nh) * 64 + y) * 128 + d] = f2b(acc[m][n][r]);
                }
            } else {
                int oo = o - 512, nh = oo >> 7, d = oo & 127;
                uint2 val;
                val.x = (unsigned int)f2b(acc[m][n][0]) | ((unsigned int)f2b(acc[m][n][1]) << 16);
                val.y = (unsigned int)f2b(acc[m][n][2]) | ((unsigned int)f2b(acc[m][n][3]) << 16);
                *(uint2*)&Vt[(size_t)((fb * 4 + nh) * 128 + d) * HWSZ + pos0] = val;
            }
        }
}

// ---------------- K2a: ph softmax over u (mt split over z for occupancy) ----------------
__global__ __launch_bounds__(256) void k_ph(const unsigned short* __restrict__ Qx,
                                            const float* __restrict__ rel_h,
                                            unsigned short* __restrict__ PH) {
    __shared__ float sm[4][16][52];
    int x = blockIdx.x, f = blockIdx.y, mtz = blockIdx.z;
    int tid = threadIdx.x, l = tid & 63, w = tid >> 6;
    int lr = l & 15, lk8 = (l >> 4) * 8;
    bf16x8 bh[3][4];
#pragma unroll
    for (int ut = 0; ut < 3; ++ut) {
        int u = ut * 16 + lr, rr = x - u + 99;
#pragma unroll
        for (int kt = 0; kt < 4; ++kt) {
            const float* s = rel_h + rr * 128 + kt * 32 + lk8;
            float4 a0 = *(const float4*)s, a1 = *(const float4*)(s + 4);
            bf16x8 pk;
            pk[0] = (short)f2b(a0.x); pk[1] = (short)f2b(a0.y); pk[2] = (short)f2b(a0.z); pk[3] = (short)f2b(a0.w);
            pk[4] = (short)f2b(a1.x); pk[5] = (short)f2b(a1.y); pk[6] = (short)f2b(a1.z); pk[7] = (short)f2b(a1.w);
            bh[ut][kt] = pk;
        }
    }
    const unsigned short* qbase = Qx + (size_t)(f * 48 + x) * 512 * 128;
    unsigned short* phbase = PH + (size_t)(f * 48 + x) * 512 * 48;
    for (int mt = mtz * 2; mt < mtz * 2 + 2; ++mt) {
        int rg = w * 128 + mt * 16 + lr;
        const unsigned short* qrow = qbase + (size_t)rg * 128;
        bf16x8 a[4];
#pragma unroll
        for (int kt = 0; kt < 4; ++kt) a[kt] = *(const bf16x8*)(qrow + kt * 32 + lk8);
        f32x4 acc[3] = {};
#pragma unroll
        for (int kt = 0; kt < 4; ++kt)
#pragma unroll
            for (int ut = 0; ut < 3; ++ut)
                acc[ut] = __builtin_amdgcn_mfma_f32_16x16x32_bf16(a[kt], bh[ut][kt], acc[ut], 0, 0, 0);
        __syncthreads();
#pragma unroll
        for (int ut = 0; ut < 3; ++ut)
#pragma unroll
            for (int r = 0; r < 4; ++r)
                sm[w][(l >> 4) * 4 + r][ut * 16 + lr] = acc[ut][r];
        __syncthreads();
        int part = l >> 4;
        float vb[12];
        float mx = -1e30f;
#pragma unroll
        for (int j = 0; j < 12; ++j) { vb[j] = sm[w][lr][part * 12 + j]; mx = fmaxf(mx, vb[j]); }
        mx = fmaxf(mx, __shfl_xor(mx, 16, 64));
        mx = fmaxf(mx, __shfl_xor(mx, 32, 64));
        float ssum = 0.f;
#pragma unroll
        for (int j = 0; j < 12; ++j) { vb[j] = __expf(vb[j] - mx); ssum += vb[j]; }
        ssum += __shfl_xor(ssum, 16, 64);
        ssum += __shfl_xor(ssum, 32, 64);
        float inv = 1.0f / ssum;
        unsigned short* dst = phbase + (size_t)(w * 128 + mt * 16 + lr) * 48 + part * 12;
#pragma unroll
        for (int j = 0; j < 12; ++j) dst[j] = f2b(vb[j] * inv);
    }
}

// ---------------- K2b: pw softmax over v (mt split over z) ----------------
__global__ __launch_bounds__(256) void k_pw(const unsigned short* __restrict__ Qx,
                                            const float* __restrict__ rel_w,
                                            unsigned short* __restrict__ PW) {
    __shared__ float sm[4][16][68];
    int y = blockIdx.x, f = blockIdx.y, mtz = blockIdx.z;
    int tid = threadIdx.x, l = tid & 63, w = tid >> 6;
    int lr = l & 15, lk8 = (l >> 4) * 8;
    bf16x8 bw[4][4];
#pragma unroll
    for (int vt = 0; vt < 4; ++vt) {
        int v = vt * 16 + lr, rr = y - v + 99;
#pragma unroll
        for (int kt = 0; kt < 4; ++kt) {
            const float* s = rel_w + rr * 128 + kt * 32 + lk8;
            float4 a0 = *(const float4*)s, a1 = *(const float4*)(s + 4);
            bf16x8 pk;
            pk[0] = (short)f2b(a0.x); pk[1] = (short)f2b(a0.y); pk[2] = (short)f2b(a0.z); pk[3] = (short)f2b(a0.w);
            pk[4] = (short)f2b(a1.x); pk[5] = (short)f2b(a1.y); pk[6] = (short)f2b(a1.z); pk[7] = (short)f2b(a1.w);
            bw[vt][kt] = pk;
        }
    }
    for (int mt = mtz * 2; mt < mtz * 2 + 2; ++mt) {
        int rg = w * 96 + mt * 16 + lr;
        int bn = rg / 48, xx = rg - bn * 48;
        const unsigned short* qrow = Qx + (size_t)((f * 48 + xx) * 512 + bn * 64 + y) * 128;
        bf16x8 a[4];
#pragma unroll
        for (int kt = 0; kt < 4; ++kt) a[kt] = *(const bf16x8*)(qrow + kt * 32 + lk8);
        f32x4 acc[4] = {};
#pragma unroll
        for (int kt = 0; kt < 4; ++kt)
#pragma unroll
            for (int vt = 0; vt < 4; ++vt)
                acc[vt] = __builtin_amdgcn_mfma_f32_16x16x32_bf16(a[kt], bw[vt][kt], acc[vt], 0, 0, 0);
        __syncthreads();
#pragma unroll
        for (int vt = 0; vt < 4; ++vt)
#pragma unroll
            for (int r = 0; r < 4; ++r)
                sm[w][(l >> 4) * 4 + r][vt * 16 + lr] = acc[vt][r];
        __syncthreads();
        int part = l >> 4;
        float vb[16];
        float mx = -1e30f;
#pragma unroll
        for (int j = 0; j < 16; ++j) { vb[j] = sm[w][lr][part * 16 + j]; mx = fmaxf(mx, vb[j]); }
        mx = fmaxf(mx, __shfl_xor(mx, 16, 64));
        mx = fmaxf(mx, __shfl_xor(mx, 32, 64));
        float ssum = 0.f;
#pragma unroll
        for (int j = 0; j < 16; ++j) { vb[j] = __expf(vb[j] - mx); ssum += vb[j]; }
        ssum += __shfl_xor(ssum, 16, 64);
        ssum += __shfl_xor(ssum, 32, 64);
        float inv = 1.0f / ssum;
        unsigned short* dst = PW + (size_t)((f * 64 + y) * 384 + rg) * 64 + part * 16;
#pragma unroll
        for (int j = 0; j < 16; ++j) dst[j] = f2b(vb[j] * inv);
    }
}

// ---------------- K3 v6: transposed MFMA, 2-u phases, depth-2 reg prefetch, counted vmcnt ----------------
// Grid 768 = (24 q-tiles x 2 d-halves) x 16 fbn; 256 threads = 4 waves, each 16d x 128q.
// Phase p covers u=2p,2p+1 (32 MFMA/wave); loads for phase p+2 issued at p; writes of p+1 at top of p.
__global__ __launch_bounds__(256, 3) void k_attn(const unsigned short* __restrict__ PH,
                                                 const unsigned short* __restrict__ PW,
                                                 const unsigned short* __restrict__ Vt,
                                                 unsigned short* __restrict__ AO) {
    __shared__ unsigned short phl[48 * 128];          // [u][(q&15)*8 + (q>>4)] bf16 (12 KB)
    __shared__ unsigned short vbuf[2][2][64 * 64];    // [buf][u-in-phase][d*64 swz] (32 KB)
    int bid = blockIdx.x;
    int r16 = bid & 15;
    int rest = bid >> 4;
    int t = rest >> 1, dh = rest & 1;
    int fbn = (r16 & 7) * 2 + (r16 >> 3);
    int f = fbn >> 3, bidx = (fbn >> 2) & 1, nh = fbn & 3;
    int fb = f * 2 + bidx, bn = bidx * 4 + nh;
    int tid = threadIdx.x;
    int l = tid & 63, wd = tid >> 6;
    int lr = l & 15, lg = l >> 4, lk8 = lg * 8;

    // V staging map: sd = tid>>3 (rows sd, sd+32), sch = tid&7 -> 2-way bank (free) on writes
    const unsigned short* vsrc = Vt + (size_t)((fb * 4 + nh) * 128 + dh * 64) * HWSZ;
    int sd = tid >> 3, sch = tid & 7;
    const unsigned short* vs0 = vsrc + (size_t)sd * HWSZ + sch * 8;
    const unsigned short* vs1 = vs0 + (size_t)32 * HWSZ;
    int wo0 = sd * 64 + ((sch ^ (sd & 7)) * 8);
    int wo1 = wo0 + 32 * 64;                           // (sd+32)&7 == sd&7

    // prologue: u0..u3 loads
    bf16x8 p0a = *(const bf16x8*)(vs0);
    bf16x8 p0b = *(const bf16x8*)(vs1);
    bf16x8 p1a = *(const bf16x8*)(vs0 + 64);
    bf16x8 p1b = *(const bf16x8*)(vs1 + 64);
    bf16x8 q0a = *(const bf16x8*)(vs0 + 128);
    bf16x8 q0b = *(const bf16x8*)(vs1 + 128);
    bf16x8 q1a = *(const bf16x8*)(vs0 + 192);
    bf16x8 q1b = *(const bf16x8*)(vs1 + 192);

    // stage ph: packed layout [u][(q&15)*8 + (q>>4)]
    for (int i = tid; i < 3072; i += 256) {
        int up2 = i >> 7, q = i & 127;
        int xy = t * 128 + q, x = xy >> 6, y = xy & 63;
        unsigned int wv = *(const unsigned int*)(PH + ((size_t)(f * 48 + x) * 512 + bn * 64 + y) * 48 + up2 * 2);
        int qoff = (q & 15) * 8 + (q >> 4);
        phl[(up2 * 2) * 128 + qoff]     = (unsigned short)(wv & 0xffffu);
        phl[(up2 * 2 + 1) * 128 + qoff] = (unsigned short)(wv >> 16);
    }
    // pw B-fragments: 8 n-frags x 2 k-halves in registers
    bf16x8 b[8][2];
#pragma unroll
    for (int n = 0; n < 8; ++n) {
        int xy = t * 128 + n * 16 + lr;
        int x = xy >> 6, y = xy & 63;
        const unsigned short* pwr = PW + ((size_t)(f * 64 + y) * 384 + bn * 48 + x) * 64;
        b[n][0] = *(const bf16x8*)(pwr + lk8);
        b[n][1] = *(const bf16x8*)(pwr + 32 + lk8);
    }
    *(bf16x8*)&vbuf[0][0][wo0] = p0a;
    *(bf16x8*)&vbuf[0][0][wo1] = p0b;
    *(bf16x8*)&vbuf[0][1][wo0] = p1a;
    *(bf16x8*)&vbuf[0][1][wo1] = p1b;
    __syncthreads();

    int arow = wd * 16 + lr;
    int ao0 = arow * 64 + ((lg ^ (arow & 7)) * 8);
    int ao1 = arow * 64 + (((4 + lg) ^ (arow & 7)) * 8);
    const unsigned short* phrow = &phl[lr * 8];
    f32x4 acc[8] = {};
    const f32x4 zero4 = {0.f, 0.f, 0.f, 0.f};
    for (int ph = 0; ph < 24; ++ph) {
        int cur = ph & 1;
        // issue loads for phase ph+2 (u = 2ph+4, 2ph+5) — in flight across 2 barriers
        bf16x8 n0a = q0a, n0b = q0b, n1a = q1a, n1b = q1b;
        if (ph + 2 < 24) {
            const unsigned short* s0 = vs0 + (size_t)(2 * ph + 4) * 64;
            const unsigned short* s1 = vs1 + (size_t)(2 * ph + 4) * 64;
            n0a = *(const bf16x8*)(s0);
            n0b = *(const bf16x8*)(s1);
            n1a = *(const bf16x8*)(s0 + 64);
            n1b = *(const bf16x8*)(s1 + 64);
        }
        // write phase ph+1 tiles (q regs, loaded one full phase ago) into the other buffer
        if (ph + 1 < 24) {
            *(bf16x8*)&vbuf[cur ^ 1][0][wo0] = q0a;
            *(bf16x8*)&vbuf[cur ^ 1][0][wo1] = q0b;
            *(bf16x8*)&vbuf[cur ^ 1][1][wo0] = q1a;
            *(bf16x8*)&vbuf[cur ^ 1][1][wo1] = q1b;
        }
        // compute u = 2ph, 2ph+1 from vbuf[cur]
#pragma unroll
        for (int uu = 0; uu < 2; ++uu) {
            int u = 2 * ph + uu;
            bf16x8 av0 = *(const bf16x8*)&vbuf[cur][uu][ao0];
            bf16x8 av1 = *(const bf16x8*)&vbuf[cur][uu][ao1];
            bf16x8 phv = *(const bf16x8*)(phrow + u * 128);
#pragma unroll
            for (int n = 0; n < 8; ++n) {
                f32x4 Y = __builtin_amdgcn_mfma_f32_16x16x32_bf16(av0, b[n][0], zero4, 0, 0, 0);
                Y = __builtin_amdgcn_mfma_f32_16x16x32_bf16(av1, b[n][1], Y, 0, 0, 0);
                float p = b2f((unsigned short)phv[n]);
                acc[n] += p * Y;
            }
        }
        __syncthreads();
        q0a = n0a; q0b = n0b; q1a = n1a; q1b = n1b;
    }
    // store: lane col q = t*128 + n*16 + lr; rows d = dh*64 + wd*16 + lg*4 (+r)
    unsigned short* aobase = AO + (size_t)fb * HWSZ * 512 + nh * 128 + dh * 64 + wd * 16 + lg * 4;
#pragma unroll
    for (int n = 0; n < 8; ++n) {
        int q = t * 128 + n * 16 + lr;
        uint2 val;
        val.x = (unsigned int)f2b(acc[n][0]) | ((unsigned int)f2b(acc[n][1]) << 16);
        val.y = (unsigned int)f2b(acc[n][2]) | ((unsigned int)f2b(acc[n][3]) << 16);
        *(uint2*)(aobase + (size_t)q * 512) = val;
    }
}

// ---------------- K4: out = fmap + gamma * (AO @ Wp^T) ----------------
__global__ __launch_bounds__(256) void k_proj(const unsigned short* __restrict__ AO,
                                              const unsigned short* __restrict__ Wpb,
                                              const float* __restrict__ f0,
                                              const float* __restrict__ f1,
                                              const float* __restrict__ gamma,
                                              float* __restrict__ out) {
    __shared__ unsigned short Asub[64 * 136];
    __shared__ unsigned short Bsub[128 * 136];
    int t = blockIdx.x, fb = blockIdx.y;
    int f = fb >> 1, bb = fb & 1;
    int tid = threadIdx.x;
    int l = tid & 63, w = tid >> 6;
    int wm = w >> 1, wn = w & 1;
    int lr = l & 15, lk8 = (l >> 4) * 8;
    f32x4 acc[2][4] = {};
    for (int ks = 0; ks < 4; ++ks) {
        if (ks) __syncthreads();
        for (int ch = tid; ch < 1024; ch += 256) {
            int row = ch >> 4, seg = ch & 15;
            *(bf16x8*)&Asub[row * 136 + seg * 8] =
                *(const bf16x8*)(AO + (size_t)(fb * HWSZ + t * 64 + row) * 512 + ks * 128 + seg * 8);
        }
        for (int ch = tid; ch < 2048; ch += 256) {
            int row = ch >> 4, seg = ch & 15;
            *(bf16x8*)&Bsub[row * 136 + seg * 8] =
                *(const bf16x8*)(Wpb + (size_t)row * 512 + ks * 128 + seg * 8);
        }
        __syncthreads();
#pragma unroll
        for (int kt = 0; kt < 4; ++kt) {
            bf16x8 a[2], b[4];
#pragma unroll
            for (int m = 0; m < 2; ++m)
                a[m] = *(const bf16x8*)&Asub[(wm * 32 + m * 16 + lr) * 136 + kt * 32 + lk8];
#pragma unroll
            for (int n = 0; n < 4; ++n)
                b[n] = *(const bf16x8*)&Bsub[(wn * 64 + n * 16 + lr) * 136 + kt * 32 + lk8];
#pragma unroll
            for (int m = 0; m < 2; ++m)
#pragma unroll
                for (int n = 0; n < 4; ++n)
                    acc[m][n] = __builtin_amdgcn_mfma_f32_16x16x32_bf16(a[m], b[n], acc[m][n], 0, 0, 0);
        }
    }
    const float* fmapf = f ? f1 : f0;
    float g = gamma[0];
#pragma unroll
    for (int m = 0; m < 2; ++m)
#pragma unroll
        for (int n = 0; n < 4; ++n) {
            int c = wn * 64 + n * 16 + lr;
            int pos0 = t * 64 + wm * 32 + m * 16 + (l >> 4) * 4;
            size_t addr = (size_t)(bb * 128 + c) * HWSZ + pos0;
            float4 fv = *(const float4*)(fmapf + addr);
            float4 ov;
            ov.x = fv.x + g * acc[m][n][0];
            ov.y = fv.y + g * acc[m][n][1];
            ov.z = fv.z + g * acc[m][n][2];
            ov.w = fv.w + g * acc[m][n][3];
            *(float4*)(out + (size_t)f * 786432 + addr) = ov;
        }
}

extern "C" void kernel_launch(void* const* d_in, const int* in_sizes, int n_in,
                              void* d_out, int out_size, void* d_ws, size_t ws_size,
                              hipStream_t stream) {
    (void)in_sizes; (void)n_in; (void)out_size; (void)ws_size;
    const float* fmap1 = (const float*)d_in[0];
    const float* fmap2 = (const float*)d_in[1];
    const float* Wqk   = (const float*)d_in[2];
    const float* Wv    = (const float*)d_in[3];
    const float* rel_h = (const float*)d_in[4];
    const float* rel_w = (const float*)d_in[5];
    const float* Wp    = (const float*)d_in[6];
    const float* gamma = (const float*)d_in[7];
    float* out = (float*)d_out;
    char* ws = (char*)d_ws;

    unsigned short* Xb   = (unsigned short*)(ws + 0);
    unsigned short* Wcat = (unsigned short*)(ws + 3145728);
    unsigned short* Wpb  = (unsigned short*)(ws + 3407872);
    unsigned short* Qx   = (unsigned short*)(ws + 3538944);
    unsigned short* AO   = Qx;                               // alias: Qx dead after K2
    unsigned short* Vt   = (unsigned short*)(ws + 16121856);
    unsigned short* PH   = (unsigned short*)(ws + 28704768);
    unsigned short* PW   = (unsigned short*)(ws + 33423360);

    k_transpose<<<dim3(96, 4, 4), dim3(32, 8), 0, stream>>>(fmap1, fmap2, Xb);
    k_weights<<<dim3(768), dim3(256), 0, stream>>>(Wqk, Wv, Wp, Wcat, Wpb);
    k_qv<<<dim3(48, 8, 4), dim3(256), 0, stream>>>(Xb, Wcat, Qx, Vt);
    k_ph<<<dim3(48, 2, 4), dim3(256), 0, stream>>>(Qx, rel_h, PH);
    k_pw<<<dim3(64, 2, 3), dim3(256), 0, stream>>>(Qx, rel_w, PW);
    k_attn<<<dim3(768), dim3(256), 0, stream>>>(PH, PW, Vt, AO);
    k_proj<<<dim3(48, 4), dim3(256), 0, stream>>>(AO, Wpb, fmap1, fmap2, gamma, out);
}